// Round 4
// baseline (1822.404 us; speedup 1.0000x reference)
//
#include <hip/hip_runtime.h>
#include <algorithm>
#include <cstdint>

// Problem constants (fixed by setup_inputs)
#define Nn 8192
#define Mm 8192
#define Dd 512
#define Cc 128

#define BT  128  // tile (n and m) for both passes
#define TK  16   // k-chunk (load-bearing for numerics; do not change)

// RA ledger (gfx950, this session): (256,2) -> 128 VGPR deterministic cap.
// R1 LESSON: merged ov[8][8] RELOAD path exceeded 128 live -> scratch thrash
// (WRITE_SIZE 8.2 GB, FETCH 3.5 GB, 2.7 ms/dispatch). Keep per-path live < 128.
// R2 LESSON: pass1 barrier halving = 0 gain; pass1 is LDS-read-throughput bound
// (8 waves x 3072 ds_read_b128 x ~12cyc = 983us model vs 935us measured).
// R3 LESSON: killing f64 exp in reload epilogue = 0 gain; pass2 not VALU-bound.
#define KERNEL_OCC __launch_bounds__(256, 2)

// ---- workspace layout (bytes); ws_size measured = 256 MiB exactly ----
#define WS_SR    0ull         // double[8192]
#define WS_SC    65536ull     // double[8192]
#define WS_CTR   131072ull    // uint[16]: 0=cand_n 1=fin_n 2=run_tb16 3=tb16 4=cbin 5=above
#define WS_GHC   131136ull    // uint[256] coarse hist
#define WS_GHF   132160ull    // uint[256] fine hist
#define WS_FINAL 133184ull    // uint2[4096]
#define WS_CAND  165952ull    // uint2[3145728] = 24 MiB (R2 ~1.53M used; same push
                              // predicate as R3 -> same volume, cap has 1.5x headroom)
#define WS_INNER 25331776ull  // float[7296*8192] = 239 MB stored inner rows
#define RSTORE   7296         // 57 of 64 block-rows stored
#define RCROWS   7            // 64 - 57 recomputed block-rows
#define WS_NEED  (WS_INNER + (size_t)RSTORE * Mm * 4ull)   // 264407104
#define FCAP     4096u

// column mapping (8 cols over 128): {tx*4..+3} and {64+tx*4..+3}
__device__ __forceinline__ int jcol(int tx, int j) {
  return (j < 4) ? tx * 4 + j : 64 + tx * 4 + (j - 4);
}

// ---------------------------------------------------------------------------
// THE inner GEMM (256 thr, 8x8/thread, 128^2 tile), DOUBLE-BUFFERED:
// one barrier per 16-k chunk. Per-element FP chain unchanged: fresh 16-fma
// chain per 16-k chunk (kk order), one add into acc2, chunks in order ->
// bit-identical (absmax 0 verified R1/R2/R3).
// ---------------------------------------------------------------------------
__device__ __forceinline__ void inner_gemm(const float* __restrict__ A,
                                           const float* __restrict__ B,
                                           int n0, int m0, int tid,
                                           float (*SA)[TK][BT], float (*SB)[TK][BT],
                                           float acc2[8][8]) {
  const int tx = tid & 15, ty = tid >> 4;
  const int lrow = tid >> 1;       // 0..127
  const int lk8  = (tid & 1) * 8;  // 0 or 8
  const float* Ap = A + (size_t)(n0 + lrow) * Dd + lk8;
  const float* Bp = B + (size_t)(m0 + lrow) * Dd + lk8;

#pragma unroll
  for (int i = 0; i < 8; ++i)
#pragma unroll
    for (int j = 0; j < 8; ++j) acc2[i][j] = 0.0f;

  float4 pa0 = *(const float4*)(Ap);
  float4 pa1 = *(const float4*)(Ap + 4);
  float4 pb0 = *(const float4*)(Bp);
  float4 pb1 = *(const float4*)(Bp + 4);

  int p = 0;
  for (int k0 = 0; k0 < Dd; k0 += TK) {
    {
      const float ar[8] = {pa0.x,pa0.y,pa0.z,pa0.w,pa1.x,pa1.y,pa1.z,pa1.w};
      const float br[8] = {pb0.x,pb0.y,pb0.z,pb0.w,pb1.x,pb1.y,pb1.z,pb1.w};
#pragma unroll
      for (int s = 0; s < 8; ++s) { SA[p][lk8 + s][lrow] = ar[s]; SB[p][lk8 + s][lrow] = br[s]; }
    }
    if (k0 + TK < Dd) {  // prefetch flies across the barrier, lands during compute
      pa0 = *(const float4*)(Ap + k0 + TK);
      pa1 = *(const float4*)(Ap + k0 + TK + 4);
      pb0 = *(const float4*)(Bp + k0 + TK);
      pb1 = *(const float4*)(Bp + k0 + TK + 4);
    }
    __syncthreads();
#pragma unroll
    for (int h = 0; h < 2; ++h) {
      float t[4][8];
#pragma unroll
      for (int i = 0; i < 4; ++i)
#pragma unroll
        for (int j = 0; j < 8; ++j) t[i][j] = 0.0f;
#pragma unroll
      for (int kk = 0; kk < TK; ++kk) {
        const float4 av  = *(const float4*)&SA[p][kk][ty * 8 + h * 4];
        const float4 bv0 = *(const float4*)&SB[p][kk][tx * 4];
        const float4 bv1 = *(const float4*)&SB[p][kk][64 + tx * 4];
        const float a[4] = {av.x, av.y, av.z, av.w};
        const float b[8] = {bv0.x,bv0.y,bv0.z,bv0.w,bv1.x,bv1.y,bv1.z,bv1.w};
#pragma unroll
        for (int i = 0; i < 4; ++i)
#pragma unroll
          for (int j = 0; j < 8; ++j) t[i][j] = fmaf(a[i], b[j], t[i][j]);
      }
#pragma unroll
      for (int i = 0; i < 4; ++i)
#pragma unroll
        for (int j = 0; j < 8; ++j) acc2[h * 4 + i][j] += t[i][j];
    }
    p ^= 1;
  }
}

// ---------------------------------------------------------------------------
// Pass 1: inner GEMM -> (store rows < RSTORE when STORE) -> exp sums (f64).
// ---------------------------------------------------------------------------
template<bool STORE>
__global__ KERNEL_OCC void k_pass1(const float* __restrict__ A,
                                   const float* __restrict__ B,
                                   double* __restrict__ Sr,
                                   double* __restrict__ Sc,
                                   float* __restrict__ inner) {
  __shared__ float SA[2][TK][BT];
  __shared__ float SB[2][TK][BT];
  __shared__ double csum[BT];
  const int tid = threadIdx.x;
  const int tx = tid & 15, ty = tid >> 4;
  const int n0 = blockIdx.y * BT, m0 = blockIdx.x * BT;

  float acc2[8][8];
  inner_gemm(A, B, n0, m0, tid, SA, SB, acc2);

  if (STORE && n0 < RSTORE) {
#pragma unroll
    for (int i = 0; i < 8; ++i) {
      float* rowp = inner + (size_t)(n0 + ty * 8 + i) * Mm + m0;
      *(float4*)(rowp + tx * 4)      = make_float4(acc2[i][0], acc2[i][1], acc2[i][2], acc2[i][3]);
      *(float4*)(rowp + 64 + tx * 4) = make_float4(acc2[i][4], acc2[i][5], acc2[i][6], acc2[i][7]);
    }
  }

  if (tid < BT) csum[tid] = 0.0;
  __syncthreads();

  float cp[8];
#pragma unroll
  for (int j = 0; j < 8; ++j) cp[j] = 0.0f;

#pragma unroll
  for (int i = 0; i < 8; ++i) {
    float r = 0.0f;
#pragma unroll
    for (int j = 0; j < 8; ++j) {
      const float e = expf(2.0f * acc2[i][j] - 2.0f);
      r += e;
      cp[j] += e;
    }
    double v = (double)r;
    v += __shfl_xor(v, 1, 16);
    v += __shfl_xor(v, 2, 16);
    v += __shfl_xor(v, 4, 16);
    v += __shfl_xor(v, 8, 16);
    if (tx == 0) atomicAdd(&Sr[n0 + ty * 8 + i], v);
  }
#pragma unroll
  for (int j = 0; j < 8; ++j) {
    double v = (double)cp[j];
    v += __shfl_xor(v, 16, 64);
    v += __shfl_xor(v, 32, 64);
    if ((tid & 63) < 16) atomicAdd(&csum[jcol(tx, j)], v);
  }
  __syncthreads();
  if (tid < BT) atomicAdd(&Sc[m0 + tid], csum[tid]);
}

// ---------------------------------------------------------------------------
__global__ void k_recip(double* __restrict__ Sr, double* __restrict__ Sc) {
  const int i = blockIdx.x * 256 + threadIdx.x;
  if (i < Nn) Sr[i] = 1.0 / Sr[i];
  if (i < Mm) Sc[i] = 1.0 / Sc[i];
}

// ---------------------------------------------------------------------------
// Select/push for one 128x64 column half.
// sb[][] = FILTER keys (exact for recompute, f32-approx for reload path).
// fe(i,j) = EXACT key, called only for pushed elements (stored in cand).
//
// R4 SKIP FAST PATH: read the device-scope running bound rb = ctr[2].
// Tightening rb requires >=256 exact keys >= rb+1; their filter keys are
// >= rb (|f16-x16| <= 1) -> if count(f16 >= rb) < 256, this block CANNOT
// tighten -> skip both histograms and scans; tb16 := rb (identical to the
// hist path's tb16 = max(ownTb<=rb, rb) = rb) -> IDENTICAL push predicate
// and volume as R2/R3's proven scheme. Early blocks (rb~0) take the full
// hist path. Staleness of rb only lowers the bound (monotone) -> still valid.
//
// R3 margin proof (F = tb16-2) unchanged: approx err ~2e-5 << fine-bin width
// -> |K16f-K16| <= 1; global top-256 element has x16 >= rb-? covered by -2.
// Final top-256 recomputed downstream from EXACT cand keys -> bit-identical.
// ---------------------------------------------------------------------------
template<typename FE>
__device__ __forceinline__ void select_push(const unsigned (*sb)[4], FE&& fe,
                                            int n0, int m0, int hh, int tid,
                                            unsigned int* h1, unsigned int* h2,
                                            unsigned int* wsum, unsigned int* sh_misc,
                                            uint2* __restrict__ cand,
                                            unsigned int* __restrict__ ctr,
                                            unsigned int cap) {
  const int tx = tid & 15, ty = tid >> 4;
  const int lane = tid & 63, wv = tid >> 6;

  // entry: zero hists (for potential hist path) + fetch running bound
  h1[tid] = 0; h2[tid] = 0;           // safe: prior reads drained by trailing barrier
  if (tid == 0) sh_misc[0] = atomicMax(&ctr[2], 0u);  // device-scope read, no modify
  __syncthreads();
  const unsigned rb = sh_misc[0];

  // skip decision: count filter keys >= rb (block-wide)
  {
    unsigned cdec = 0;
#pragma unroll
    for (int i = 0; i < 8; ++i)
#pragma unroll
      for (int j = 0; j < 4; ++j) cdec += ((sb[i][j] >> 16) >= rb) ? 1u : 0u;
#pragma unroll
    for (int d = 1; d < 64; d <<= 1) cdec += __shfl_down(cdec, d, 64);
    if (lane == 0) wsum[wv] = cdec;
  }
  __syncthreads();
  if (tid == 0) sh_misc[1] = wsum[0] + wsum[1] + wsum[2] + wsum[3];
  __syncthreads();
  const bool skip = sh_misc[1] < 256u;

  unsigned tb16;
  if (!skip) {
    // ---- full two-level histogram threshold (proven path) ----
#pragma unroll
    for (int i = 0; i < 8; ++i)
#pragma unroll
      for (int j = 0; j < 4; ++j) atomicAdd(&h1[sb[i][j] >> 24], 1u);
    __syncthreads();
    if (tid < 64) {  // wave 0: coarse threshold scan
      const int b0 = tid * 4;
      const unsigned s4 = h1[b0] + h1[b0 + 1] + h1[b0 + 2] + h1[b0 + 3];
      unsigned suf = s4;
#pragma unroll
      for (int d = 1; d < 64; d <<= 1) {
        const unsigned v = __shfl_down(suf, d, 64);
        if (tid + d < 64) suf += v;
      }
      const unsigned long long mk = __ballot(suf >= 256u);  // suf decreasing -> prefix mask
      const int L = 63 - __builtin_clzll(mk);               // total >= 256 -> mk != 0
      if (tid == L) {
        unsigned cum = suf - s4;        // count strictly above lane L's bins
        unsigned cb = (unsigned)(4 * L), abv = cum;
        for (int b = 4 * L + 3; b >= 4 * L; --b) {
          const unsigned nc = cum + h1[b];
          if (nc >= 256u) { cb = (unsigned)b; abv = cum; break; }
          cum = nc;
        }
        sh_misc[0] = cb; sh_misc[1] = abv;
      }
    }
    __syncthreads();
    const unsigned cb = sh_misc[0], above = sh_misc[1];
#pragma unroll
    for (int i = 0; i < 8; ++i)
#pragma unroll
      for (int j = 0; j < 4; ++j)
        if ((sb[i][j] >> 24) == cb) atomicAdd(&h2[(sb[i][j] >> 16) & 0xFFu], 1u);
    __syncthreads();
    if (tid < 64) {  // wave 0: fine threshold scan
      const int b0 = tid * 4;
      const unsigned s4 = h2[b0] + h2[b0 + 1] + h2[b0 + 2] + h2[b0 + 3];
      unsigned suf = s4;
#pragma unroll
      for (int d = 1; d < 64; d <<= 1) {
        const unsigned v = __shfl_down(suf, d, 64);
        if (tid + d < 64) suf += v;
      }
      const unsigned long long mk = __ballot(above + suf >= 256u);
      const int L = 63 - __builtin_clzll(mk);
      if (tid == L) {
        unsigned cum = above + suf - s4;
        unsigned tb = cb << 8;
        for (int b = 4 * L + 3; b >= 4 * L; --b) {
          cum += h2[b];
          if (cum >= 256u) { tb = (cb << 8) | (unsigned)b; break; }
        }
        const unsigned old = atomicMax(&ctr[2], tb);  // device-scope tighten
        sh_misc[2] = tb > old ? tb : old;
      }
    }
    __syncthreads();
    tb16 = sh_misc[2];
  } else {
    tb16 = rb;   // own Tb <= rb (proven by the count) -> identical tb16
  }
  const unsigned F = tb16 > 2u ? tb16 - 2u : 0u;   // 2-fine-bin relaxation

  // candidate push: wave shuffle-scan + 4-entry serial base
  unsigned cnt = 0;
#pragma unroll
  for (int i = 0; i < 8; ++i)
#pragma unroll
    for (int j = 0; j < 4; ++j) cnt += ((sb[i][j] >> 16) >= F) ? 1u : 0u;
  unsigned incl = cnt;
#pragma unroll
  for (int d = 1; d < 64; d <<= 1) {
    const unsigned nv = __shfl_up(incl, d, 64);
    if (lane >= d) incl += nv;
  }
  if (lane == 63) wsum[wv] = incl;
  __syncthreads();
  if (tid == 0) {
    unsigned run = 0;
#pragma unroll
    for (int w = 0; w < 4; ++w) { const unsigned c = wsum[w]; wsum[w] = run; run += c; }
    sh_misc[3] = atomicAdd(&ctr[0], run);
  }
  __syncthreads();
  unsigned pos = sh_misc[3] + wsum[wv] + incl - cnt;
#pragma unroll
  for (int i = 0; i < 8; ++i)
#pragma unroll
    for (int j = 0; j < 4; ++j) {
      if ((sb[i][j] >> 16) >= F) {
        if (pos < cap) {
          const unsigned idxv = ((unsigned)(n0 + ty * 8 + i) << 13)
                              | (unsigned)(m0 + hh * 64 + tx * 4 + j);
          cand[pos] = make_uint2(fe(i, j), idxv);   // EXACT key stored
        }
        ++pos;
      }
    }
  __syncthreads();  // h1/h2/wsum/sh_misc reuse in next half
}

// ---------------------------------------------------------------------------
// Pass 2 — SINGLE dispatch, runtime reload/recompute branch (R4).
// mode 0 (store): blockIdx.y in [0,7)  -> RECOMPUTE rows 57+y (dispatched
//   FIRST -> their long pole hides under the 3648 reload blocks);
//   blockIdx.y in [7,64) -> RELOAD row y-7.
// mode 1 (no store): all recompute, row = blockIdx.y.
// Reload path: DB-staged overlap GEMM ov[8][4]; approx f32 filter keys;
//   exact f64 keys only for pushed elements. Live ~116 < 128 cap.
// Recompute path: proven per-half structure, exact keys throughout.
// ---------------------------------------------------------------------------
__global__ KERNEL_OCC void k_pass2(
    const float* __restrict__ A, const float* __restrict__ B,
    const float* __restrict__ C0, const float* __restrict__ C1,
    const double* __restrict__ invSr, const double* __restrict__ invSc,
    const float* __restrict__ inner, int mode,
    uint2* __restrict__ cand, unsigned int* __restrict__ ctr, unsigned int cap) {
  __shared__ float SA[2][TK][BT];
  __shared__ float SB[2][TK][BT];
  __shared__ unsigned int h1[256];
  __shared__ unsigned int h2[256];
  __shared__ unsigned int wsum[4];
  __shared__ unsigned int sh_misc[4];
  __shared__ double dsr[BT];
  __shared__ double dsc[BT];
  __shared__ float dsrf[BT];
  __shared__ float dscf[BT];
  const int tid = threadIdx.x;
  const int tx = tid & 15, ty = tid >> 4;

  bool reload;
  int nrow;
  if (mode == 0) {
    reload = (blockIdx.y >= RCROWS);
    nrow = reload ? (int)blockIdx.y - RCROWS : RSTORE / BT + (int)blockIdx.y;
  } else {
    reload = false;
    nrow = (int)blockIdx.y;
  }
  const int n0 = nrow * BT, m0 = blockIdx.x * BT;

  // f64 normalizers -> LDS once (same bits) + f32 mirrors for approx keys
  if (tid < BT) {
    const double v = invSr[n0 + tid];
    dsr[tid] = v; dsrf[tid] = (float)v;
  } else {
    const double v = invSc[m0 + tid - BT];
    dsc[tid - BT] = v; dscf[tid - BT] = (float)v;
  }

  const int frow = tid >> 4;        // 0..15 staging row
  const int fn   = (tid & 15) * 8;  // 0..120 staging col

  if (reload) {
#pragma unroll 1
    for (int hh = 0; hh < 2; ++hh) {
      // ---- overlap GEMM for this half, double-buffered staging ----
      float ov[8][4];
#pragma unroll
      for (int i = 0; i < 8; ++i)
#pragma unroll
        for (int j = 0; j < 4; ++j) ov[i][j] = 0.0f;

      const float* c0p = C0 + (size_t)frow * Nn + n0 + fn;
      const float* c1p = C1 + (size_t)frow * Mm + m0 + fn;
      float4 ca0 = *(const float4*)(c0p);
      float4 ca1 = *(const float4*)(c0p + 4);
      float4 cb0 = *(const float4*)(c1p);
      float4 cb1 = *(const float4*)(c1p + 4);
      int p = 0;
      for (int c0i = 0; c0i < Cc; c0i += TK) {
        *(float4*)&SA[p][frow][fn]     = ca0;
        *(float4*)&SA[p][frow][fn + 4] = ca1;
        *(float4*)&SB[p][frow][fn]     = cb0;
        *(float4*)&SB[p][frow][fn + 4] = cb1;
        if (c0i + TK < Cc) {
          const size_t off = (size_t)(c0i + TK);
          ca0 = *(const float4*)(c0p + off * Nn);
          ca1 = *(const float4*)(c0p + off * Nn + 4);
          cb0 = *(const float4*)(c1p + off * Mm);
          cb1 = *(const float4*)(c1p + off * Mm + 4);
        }
        __syncthreads();
#pragma unroll
        for (int g = 0; g < 2; ++g) {
          float th[4][4];
#pragma unroll
          for (int i = 0; i < 4; ++i)
#pragma unroll
            for (int j = 0; j < 4; ++j) th[i][j] = 0.0f;
#pragma unroll
          for (int kk = 0; kk < TK; ++kk) {
            const float4 av = *(const float4*)&SA[p][kk][ty * 8 + g * 4];
            const float4 bv = *(const float4*)&SB[p][kk][hh * 64 + tx * 4];
            const float a[4] = {av.x, av.y, av.z, av.w};
            const float b[4] = {bv.x, bv.y, bv.z, bv.w};
#pragma unroll
            for (int i = 0; i < 4; ++i)
#pragma unroll
              for (int j = 0; j < 4; ++j) th[i][j] = fmaf(a[i], b[j], th[i][j]);
          }
#pragma unroll
          for (int i = 0; i < 4; ++i)
#pragma unroll
            for (int j = 0; j < 4; ++j) ov[g * 4 + i][j] += th[i][j];
        }
        p ^= 1;
      }

      // ---- reload stored f32 inner bits -> APPROX f32 keys ----
      float af[8][4];
      unsigned sb[8][4];
#pragma unroll
      for (int i = 0; i < 8; ++i) {
        *(float4*)&af[i][0] = *(const float4*)(inner + (size_t)(n0 + ty * 8 + i) * Mm
                                               + m0 + hh * 64 + tx * 4);
#pragma unroll
        for (int j = 0; j < 4; ++j) {
          const float ef = __expf(2.0f * af[i][j] - 2.0f);
          const float sf = ef * ef * dsrf[ty * 8 + i] * dscf[hh * 64 + tx * 4 + j]
                         * ov[i][j];
          sb[i][j] = __float_as_uint(sf);
        }
      }
      // exact key on demand (bit-identical chain to R2's epilogue)
      auto fe = [&](int i, int j) -> unsigned {
        const double e = exp(2.0 * (double)af[i][j] - 2.0);
        const double s = e * e * dsr[ty * 8 + i] * dsc[hh * 64 + tx * 4 + j]
                       * (double)ov[i][j];
        return __float_as_uint((float)s);
      };
      select_push(sb, fe, n0, m0, hh, tid, h1, h2, wsum, sh_misc, cand, ctr, cap);
    }
  } else {
    // ---- recompute path: proven per-half structure, exact keys throughout ----
    float acc2[8][8];
    inner_gemm(A, B, n0, m0, tid, SA, SB, acc2);

#pragma unroll 1
    for (int hh = 0; hh < 2; ++hh) {
      float ov[8][4];
#pragma unroll
      for (int i = 0; i < 8; ++i)
#pragma unroll
        for (int j = 0; j < 4; ++j) ov[i][j] = 0.0f;
      for (int c0i = 0; c0i < Cc; c0i += TK) {
        __syncthreads();
        *(float4*)&SA[0][frow][fn]     = *(const float4*)(C0 + (size_t)(c0i + frow) * Nn + n0 + fn);
        *(float4*)&SA[0][frow][fn + 4] = *(const float4*)(C0 + (size_t)(c0i + frow) * Nn + n0 + fn + 4);
        *(float4*)&SB[0][frow][fn]     = *(const float4*)(C1 + (size_t)(c0i + frow) * Mm + m0 + fn);
        *(float4*)&SB[0][frow][fn + 4] = *(const float4*)(C1 + (size_t)(c0i + frow) * Mm + m0 + fn + 4);
        __syncthreads();
#pragma unroll
        for (int g = 0; g < 2; ++g) {
          float th[4][4];
#pragma unroll
          for (int i = 0; i < 4; ++i)
#pragma unroll
            for (int j = 0; j < 4; ++j) th[i][j] = 0.0f;
#pragma unroll
          for (int kk = 0; kk < TK; ++kk) {
            const float4 av = *(const float4*)&SA[0][kk][ty * 8 + g * 4];
            const float4 bv = *(const float4*)&SB[0][kk][hh * 64 + tx * 4];
            const float a[4] = {av.x, av.y, av.z, av.w};
            const float b[4] = {bv.x, bv.y, bv.z, bv.w};
#pragma unroll
            for (int i = 0; i < 4; ++i)
#pragma unroll
              for (int j = 0; j < 4; ++j) th[i][j] = fmaf(a[i], b[j], th[i][j]);
          }
#pragma unroll
          for (int i = 0; i < 4; ++i)
#pragma unroll
            for (int j = 0; j < 4; ++j) ov[g * 4 + i][j] += th[i][j];
        }
      }

      unsigned sb[8][4];
#pragma unroll
      for (int i = 0; i < 8; ++i)
#pragma unroll
        for (int j = 0; j < 4; ++j) {
          const double e = exp(2.0 * (double)acc2[i][hh * 4 + j] - 2.0);
          const double s = e * e * dsr[ty * 8 + i] * dsc[hh * 64 + tx * 4 + j]
                         * (double)ov[i][j];
          sb[i][j] = __float_as_uint(s);
        }
      auto fe = [&](int i, int j) -> unsigned { return sb[i][j]; };
      select_push(sb, fe, n0, m0, hh, tid, h1, h2, wsum, sh_misc, cand, ctr, cap);
    }
  }
}

// ---------------------------------------------------------------------------
// Tail: LDS-aggregated coarse(8b) + fine(8b) histograms -> threshold -> collect
// -> sort. (Unchanged — a few µs total; operates on EXACT cand keys.)
// ---------------------------------------------------------------------------
__global__ __launch_bounds__(256) void k_histc(const uint2* __restrict__ cand,
                                               const unsigned int* __restrict__ ctr,
                                               unsigned int cap,
                                               unsigned int* __restrict__ ghc) {
  __shared__ unsigned int lh[256];
  const int tid = threadIdx.x;
  lh[tid] = 0;
  __syncthreads();
  const unsigned n = min(ctr[0], cap);
  const unsigned stride = gridDim.x * blockDim.x;
  for (unsigned i = blockIdx.x * blockDim.x + tid; i < n; i += stride)
    atomicAdd(&lh[cand[i].x >> 24], 1u);
  __syncthreads();
  if (lh[tid]) atomicAdd(&ghc[tid], lh[tid]);
}

__global__ __launch_bounds__(256) void k_threshc(const unsigned int* __restrict__ ghc,
                                                 unsigned int* __restrict__ ctr) {
  __shared__ unsigned int g[256];
  const int tid = threadIdx.x;
  g[tid] = ghc[tid];
  __syncthreads();
  if (tid == 0) {
    unsigned cum = 0;
    for (int b = 255; b >= 0; --b) {
      cum += g[b];
      if (cum >= 256u) { ctr[4] = (unsigned)b; ctr[5] = cum - g[b]; break; }
    }
  }
}

__global__ __launch_bounds__(256) void k_histf(const uint2* __restrict__ cand,
                                               const unsigned int* __restrict__ ctr,
                                               unsigned int cap,
                                               unsigned int* __restrict__ ghf) {
  __shared__ unsigned int lh[256];
  const int tid = threadIdx.x;
  lh[tid] = 0;
  __syncthreads();
  const unsigned n = min(ctr[0], cap);
  const unsigned cb = ctr[4];
  const unsigned stride = gridDim.x * blockDim.x;
  for (unsigned i = blockIdx.x * blockDim.x + tid; i < n; i += stride) {
    const unsigned k = cand[i].x;
    if ((k >> 24) == cb) atomicAdd(&lh[(k >> 16) & 0xFFu], 1u);
  }
  __syncthreads();
  if (lh[tid]) atomicAdd(&ghf[tid], lh[tid]);
}

__global__ __launch_bounds__(256) void k_threshf(const unsigned int* __restrict__ ghf,
                                                 unsigned int* __restrict__ ctr) {
  __shared__ unsigned int g[256];
  const int tid = threadIdx.x;
  g[tid] = ghf[tid];
  __syncthreads();
  if (tid == 0) {
    const unsigned cb = ctr[4];
    unsigned cum = ctr[5], tb = cb << 8;
    for (int b = 255; b >= 0; --b) {
      cum += g[b];
      if (cum >= 256u) { tb = (cb << 8) | (unsigned)b; break; }
    }
    ctr[3] = tb;
  }
}

__global__ void k_collect(const uint2* __restrict__ cand,
                          unsigned int* __restrict__ ctr,
                          unsigned int cap, uint2* __restrict__ fin) {
  const unsigned n = min(ctr[0], cap);
  const unsigned tb = ctr[3];
  const unsigned stride = gridDim.x * blockDim.x;
  for (unsigned i = blockIdx.x * blockDim.x + threadIdx.x; i < n; i += stride) {
    const uint2 c = cand[i];
    if ((c.x >> 16) >= tb) {
      const unsigned p = atomicAdd(&ctr[1], 1u);
      if (p < FCAP) fin[p] = c;
    }
  }
}

// Sort: pack (key, ~idx) into u64, bitonic desc -> (key desc, idx asc) —
// exactly lax.top_k / np tie semantics on the f32 scores.
__global__ __launch_bounds__(256) void k_sort(const uint2* __restrict__ fin,
                                              const unsigned int* __restrict__ ctr,
                                              float* __restrict__ out) {
  __shared__ unsigned long long kk[FCAP];
  const int tid = threadIdx.x;
  const unsigned n = min(ctr[1], FCAP);
  unsigned np2 = 256;
  while (np2 < n) np2 <<= 1;
  for (unsigned i = tid; i < np2; i += 256) {
    if (i < n) {
      const uint2 c = fin[i];
      kk[i] = ((unsigned long long)c.x << 32) | (unsigned long long)(c.y ^ 0xFFFFFFFFu);
    } else {
      kk[i] = 0ull;
    }
  }
  __syncthreads();
  for (unsigned k2 = 2; k2 <= np2; k2 <<= 1) {
    for (unsigned j = k2 >> 1; j > 0; j >>= 1) {
      for (unsigned i = tid; i < np2; i += 256) {
        const unsigned l = i ^ j;
        if (l > i) {
          const unsigned long long ka = kk[i], kb = kk[l];
          const bool aBefore = ka > kb;
          const bool dsc = (i & k2) == 0;
          const bool sw = dsc ? !aBefore : aBefore;
          if (sw) { kk[i] = kb; kk[l] = ka; }
        }
      }
      __syncthreads();
    }
  }
  {
    const unsigned long long kv = kk[tid];
    const unsigned key = (unsigned)(kv >> 32);
    const unsigned ix  = ((unsigned)kv) ^ 0xFFFFFFFFu;
    out[tid]        = (float)(ix >> 13);      // ref_corr_indices
    out[256 + tid]  = (float)(ix & 8191u);    // src_corr_indices
    out[512 + tid]  = __uint_as_float(key);   // corr_scores (same f32 bits)
  }
}

// ---------------------------------------------------------------------------
extern "C" void kernel_launch(void* const* d_in, const int* in_sizes, int n_in,
                              void* d_out, int out_size, void* d_ws, size_t ws_size,
                              hipStream_t stream) {
  (void)in_sizes; (void)n_in; (void)out_size;
  const float* ref = (const float*)d_in[0];
  const float* src = (const float*)d_in[1];
  const float* c0  = (const float*)d_in[2];
  const float* c1  = (const float*)d_in[3];
  char* ws = (char*)d_ws;
  double* Sr = (double*)(ws + WS_SR);
  double* Sc = (double*)(ws + WS_SC);
  unsigned int* ctr = (unsigned int*)(ws + WS_CTR);
  unsigned int* ghc = (unsigned int*)(ws + WS_GHC);
  unsigned int* ghf = (unsigned int*)(ws + WS_GHF);
  uint2* fin   = (uint2*)(ws + WS_FINAL);
  uint2* cand  = (uint2*)(ws + WS_CAND);
  float* inner = (float*)(ws + WS_INNER);

  const bool store = ws_size >= (size_t)WS_NEED;
  unsigned int cap;
  if (store) {
    cap = (unsigned int)((WS_INNER - WS_CAND) / 8);   // 3,145,728
  } else {
    cap = (ws_size > WS_CAND + 8)
        ? (unsigned int)std::min<size_t>((ws_size - WS_CAND) / 8, (size_t)(16u << 20))
        : 0u;
  }

  hipMemsetAsync(d_ws, 0, (size_t)WS_FINAL, stream);  // Sr, Sc, ctr, ghc, ghf

  dim3 g1(Mm / BT, Nn / BT);
  if (store) {
    k_pass1<true><<<g1, 256, 0, stream>>>(ref, src, Sr, Sc, inner);
    k_recip<<<32, 256, 0, stream>>>(Sr, Sc);
    // single merged dispatch: y<7 recompute rows 57..63 (scheduled first),
    // y>=7 reload rows 0..56
    k_pass2<<<dim3(Mm / BT, Nn / BT), 256, 0, stream>>>(
        ref, src, c0, c1, Sr, Sc, inner, 0, cand, ctr, cap);
  } else {
    k_pass1<false><<<g1, 256, 0, stream>>>(ref, src, Sr, Sc, nullptr);
    k_recip<<<32, 256, 0, stream>>>(Sr, Sc);
    k_pass2<<<g1, 256, 0, stream>>>(ref, src, c0, c1, Sr, Sc, nullptr, 1, cand, ctr, cap);
  }
  k_histc<<<256, 256, 0, stream>>>(cand, ctr, cap, ghc);
  k_threshc<<<1, 256, 0, stream>>>(ghc, ctr);
  k_histf<<<256, 256, 0, stream>>>(cand, ctr, cap, ghf);
  k_threshf<<<1, 256, 0, stream>>>(ghf, ctr);
  k_collect<<<256, 256, 0, stream>>>(cand, ctr, cap, fin);
  k_sort<<<1, 256, 0, stream>>>(fin, ctr, (float*)d_out);
}

// Round 5
// 1696.919 us; speedup vs baseline: 1.0739x; 1.0739x over previous
//
#include <hip/hip_runtime.h>
#include <algorithm>
#include <cstdint>

// Problem constants (fixed by setup_inputs)
#define Nn 8192
#define Mm 8192
#define Dd 512
#define Cc 128

#define BT  128  // tile (n and m) for both passes
#define TK  16   // k-chunk (load-bearing for numerics; do not change)

// RA ledger (gfx950, this session):
//   (256,2) -> 128 VGPR deterministic cap; (256,1) -> up to 256.
// R1: merged ov[8][8] reload path > 128 live -> scratch thrash (8 GB writes).
// R2: pass1 barrier halving = 0 gain; pass1 is LDS-ISSUE bound
//     (6 ds_read_b128/kk: model 983us vs 935us measured).
// R3: killing f64 exp in reload epilogue = 0 gain; select/epilogue not the cost.
// R4: skip-path + merged pass2 dispatch = -100us REGRESSION; reverted. Select
//     phase is CLOSED as a target.
// R5: pass1 -> 4 reads/kk t[8][8] form at (256,1): LDS work 2.36M -> 1.57M
//     cyc/CU (model 655us). ~170 VGPR -> 3 waves/SIMD, LDS pipe still saturated.
#define KERNEL_OCC    __launch_bounds__(256, 2)
#define KERNEL_OCC_P1 __launch_bounds__(256, 1)

// ---- workspace layout (bytes); ws_size measured = 256 MiB exactly ----
#define WS_SR    0ull         // double[8192]
#define WS_SC    65536ull     // double[8192]
#define WS_CTR   131072ull    // uint[16]: 0=cand_n 1=fin_n 2=run_tb16 3=tb16 4=cbin 5=above
#define WS_GHC   131136ull    // uint[256] coarse hist
#define WS_GHF   132160ull    // uint[256] fine hist
#define WS_FINAL 133184ull    // uint2[4096]
#define WS_CAND  165952ull    // uint2[3145728] = 24 MiB (~2M used with -2 relaxation)
#define WS_INNER 25331776ull  // float[7296*8192] = 239 MB stored inner rows
#define RSTORE   7296         // 57 of 64 block-rows stored
#define WS_NEED  (WS_INNER + (size_t)RSTORE * Mm * 4ull)   // 264407104
#define FCAP     4096u

// column mapping (8 cols over 128): {tx*4..+3} and {64+tx*4..+3}
__device__ __forceinline__ int jcol(int tx, int j) {
  return (j < 4) ? tx * 4 + j : 64 + tx * 4 + (j - 4);
}

// ---------------------------------------------------------------------------
// WIDE inner GEMM for pass1 (R5): 4 ds_read_b128 per kk (was 6), full t[8][8]
// per chunk. Needs ~170 VGPR -> pass1 runs at (256,1).
// FP chain PER ELEMENT is bit-identical to the proven version: fresh t=0 per
// 16-k chunk, fma chain over kk ascending, ONE add into acc2 per chunk,
// chunks in order. Only the cross-element interleave changed (h-split removed),
// which cannot affect any element's bits.
// ---------------------------------------------------------------------------
__device__ __forceinline__ void inner_gemm_wide(const float* __restrict__ A,
                                                const float* __restrict__ B,
                                                int n0, int m0, int tid,
                                                float (*SA)[TK][BT], float (*SB)[TK][BT],
                                                float acc2[8][8]) {
  const int tx = tid & 15, ty = tid >> 4;
  const int lrow = tid >> 1;       // 0..127
  const int lk8  = (tid & 1) * 8;  // 0 or 8
  const float* Ap = A + (size_t)(n0 + lrow) * Dd + lk8;
  const float* Bp = B + (size_t)(m0 + lrow) * Dd + lk8;

#pragma unroll
  for (int i = 0; i < 8; ++i)
#pragma unroll
    for (int j = 0; j < 8; ++j) acc2[i][j] = 0.0f;

  float4 pa0 = *(const float4*)(Ap);
  float4 pa1 = *(const float4*)(Ap + 4);
  float4 pb0 = *(const float4*)(Bp);
  float4 pb1 = *(const float4*)(Bp + 4);

  int p = 0;
  for (int k0 = 0; k0 < Dd; k0 += TK) {
    {
      const float ar[8] = {pa0.x,pa0.y,pa0.z,pa0.w,pa1.x,pa1.y,pa1.z,pa1.w};
      const float br[8] = {pb0.x,pb0.y,pb0.z,pb0.w,pb1.x,pb1.y,pb1.z,pb1.w};
#pragma unroll
      for (int s = 0; s < 8; ++s) { SA[p][lk8 + s][lrow] = ar[s]; SB[p][lk8 + s][lrow] = br[s]; }
    }
    if (k0 + TK < Dd) {  // prefetch flies across the barrier, lands during compute
      pa0 = *(const float4*)(Ap + k0 + TK);
      pa1 = *(const float4*)(Ap + k0 + TK + 4);
      pb0 = *(const float4*)(Bp + k0 + TK);
      pb1 = *(const float4*)(Bp + k0 + TK + 4);
    }
    __syncthreads();

    float t[8][8];
#pragma unroll
    for (int i = 0; i < 8; ++i)
#pragma unroll
      for (int j = 0; j < 8; ++j) t[i][j] = 0.0f;
#pragma unroll
    for (int kk = 0; kk < TK; ++kk) {
      const float4 av0 = *(const float4*)&SA[p][kk][ty * 8];
      const float4 av1 = *(const float4*)&SA[p][kk][ty * 8 + 4];
      const float4 bv0 = *(const float4*)&SB[p][kk][tx * 4];
      const float4 bv1 = *(const float4*)&SB[p][kk][64 + tx * 4];
      const float a[8] = {av0.x,av0.y,av0.z,av0.w,av1.x,av1.y,av1.z,av1.w};
      const float b[8] = {bv0.x,bv0.y,bv0.z,bv0.w,bv1.x,bv1.y,bv1.z,bv1.w};
#pragma unroll
      for (int i = 0; i < 8; ++i)
#pragma unroll
        for (int j = 0; j < 8; ++j) t[i][j] = fmaf(a[i], b[j], t[i][j]);
    }
#pragma unroll
    for (int i = 0; i < 8; ++i)
#pragma unroll
      for (int j = 0; j < 8; ++j) acc2[i][j] += t[i][j];
    p ^= 1;
  }
}

// ---------------------------------------------------------------------------
// SPLIT inner GEMM (6 reads/kk, t[4][8] halves) — kept for pass2 recompute,
// which must stay at (256,2)/128 VGPR. Bit-identical chain (proven R1-R4).
// ---------------------------------------------------------------------------
__device__ __forceinline__ void inner_gemm(const float* __restrict__ A,
                                           const float* __restrict__ B,
                                           int n0, int m0, int tid,
                                           float (*SA)[TK][BT], float (*SB)[TK][BT],
                                           float acc2[8][8]) {
  const int tx = tid & 15, ty = tid >> 4;
  const int lrow = tid >> 1;       // 0..127
  const int lk8  = (tid & 1) * 8;  // 0 or 8
  const float* Ap = A + (size_t)(n0 + lrow) * Dd + lk8;
  const float* Bp = B + (size_t)(m0 + lrow) * Dd + lk8;

#pragma unroll
  for (int i = 0; i < 8; ++i)
#pragma unroll
    for (int j = 0; j < 8; ++j) acc2[i][j] = 0.0f;

  float4 pa0 = *(const float4*)(Ap);
  float4 pa1 = *(const float4*)(Ap + 4);
  float4 pb0 = *(const float4*)(Bp);
  float4 pb1 = *(const float4*)(Bp + 4);

  int p = 0;
  for (int k0 = 0; k0 < Dd; k0 += TK) {
    {
      const float ar[8] = {pa0.x,pa0.y,pa0.z,pa0.w,pa1.x,pa1.y,pa1.z,pa1.w};
      const float br[8] = {pb0.x,pb0.y,pb0.z,pb0.w,pb1.x,pb1.y,pb1.z,pb1.w};
#pragma unroll
      for (int s = 0; s < 8; ++s) { SA[p][lk8 + s][lrow] = ar[s]; SB[p][lk8 + s][lrow] = br[s]; }
    }
    if (k0 + TK < Dd) {
      pa0 = *(const float4*)(Ap + k0 + TK);
      pa1 = *(const float4*)(Ap + k0 + TK + 4);
      pb0 = *(const float4*)(Bp + k0 + TK);
      pb1 = *(const float4*)(Bp + k0 + TK + 4);
    }
    __syncthreads();
#pragma unroll
    for (int h = 0; h < 2; ++h) {
      float t[4][8];
#pragma unroll
      for (int i = 0; i < 4; ++i)
#pragma unroll
        for (int j = 0; j < 8; ++j) t[i][j] = 0.0f;
#pragma unroll
      for (int kk = 0; kk < TK; ++kk) {
        const float4 av  = *(const float4*)&SA[p][kk][ty * 8 + h * 4];
        const float4 bv0 = *(const float4*)&SB[p][kk][tx * 4];
        const float4 bv1 = *(const float4*)&SB[p][kk][64 + tx * 4];
        const float a[4] = {av.x, av.y, av.z, av.w};
        const float b[8] = {bv0.x,bv0.y,bv0.z,bv0.w,bv1.x,bv1.y,bv1.z,bv1.w};
#pragma unroll
        for (int i = 0; i < 4; ++i)
#pragma unroll
          for (int j = 0; j < 8; ++j) t[i][j] = fmaf(a[i], b[j], t[i][j]);
      }
#pragma unroll
      for (int i = 0; i < 4; ++i)
#pragma unroll
        for (int j = 0; j < 8; ++j) acc2[h * 4 + i][j] += t[i][j];
    }
    p ^= 1;
  }
}

// ---------------------------------------------------------------------------
// Pass 1: wide inner GEMM -> (store rows < RSTORE when STORE) -> exp sums (f64).
// (256,1): ~170 VGPR -> 3 waves/SIMD; LDS-pipe total work is occupancy-
// independent, so the 1.5x read reduction converts directly to time.
// ---------------------------------------------------------------------------
template<bool STORE>
__global__ KERNEL_OCC_P1 void k_pass1(const float* __restrict__ A,
                                      const float* __restrict__ B,
                                      double* __restrict__ Sr,
                                      double* __restrict__ Sc,
                                      float* __restrict__ inner) {
  __shared__ float SA[2][TK][BT];
  __shared__ float SB[2][TK][BT];
  __shared__ double csum[BT];
  const int tid = threadIdx.x;
  const int tx = tid & 15, ty = tid >> 4;
  const int n0 = blockIdx.y * BT, m0 = blockIdx.x * BT;

  float acc2[8][8];
  inner_gemm_wide(A, B, n0, m0, tid, SA, SB, acc2);

  if (STORE && n0 < RSTORE) {
#pragma unroll
    for (int i = 0; i < 8; ++i) {
      float* rowp = inner + (size_t)(n0 + ty * 8 + i) * Mm + m0;
      *(float4*)(rowp + tx * 4)      = make_float4(acc2[i][0], acc2[i][1], acc2[i][2], acc2[i][3]);
      *(float4*)(rowp + 64 + tx * 4) = make_float4(acc2[i][4], acc2[i][5], acc2[i][6], acc2[i][7]);
    }
  }

  if (tid < BT) csum[tid] = 0.0;
  __syncthreads();

  float cp[8];
#pragma unroll
  for (int j = 0; j < 8; ++j) cp[j] = 0.0f;

#pragma unroll
  for (int i = 0; i < 8; ++i) {
    float r = 0.0f;
#pragma unroll
    for (int j = 0; j < 8; ++j) {
      const float e = expf(2.0f * acc2[i][j] - 2.0f);
      r += e;
      cp[j] += e;
    }
    double v = (double)r;
    v += __shfl_xor(v, 1, 16);
    v += __shfl_xor(v, 2, 16);
    v += __shfl_xor(v, 4, 16);
    v += __shfl_xor(v, 8, 16);
    if (tx == 0) atomicAdd(&Sr[n0 + ty * 8 + i], v);
  }
#pragma unroll
  for (int j = 0; j < 8; ++j) {
    double v = (double)cp[j];
    v += __shfl_xor(v, 16, 64);
    v += __shfl_xor(v, 32, 64);
    if ((tid & 63) < 16) atomicAdd(&csum[jcol(tx, j)], v);
  }
  __syncthreads();
  if (tid < BT) atomicAdd(&Sc[m0 + tid], csum[tid]);
}

// ---------------------------------------------------------------------------
__global__ void k_recip(double* __restrict__ Sr, double* __restrict__ Sc) {
  const int i = blockIdx.x * 256 + threadIdx.x;
  if (i < Nn) Sr[i] = 1.0 / Sr[i];
  if (i < Mm) Sc[i] = 1.0 / Sc[i];
}

// ---------------------------------------------------------------------------
// Select/push for one 128x64 column half (R3-proven version; R4 skip-path
// reverted). sb = filter keys (exact recompute / f32-approx reload);
// fe(i,j) = exact key, computed only for pushed elements.
// F = tb16-2 relaxation proof in R3 notes; downstream top-256 from exact keys.
// ---------------------------------------------------------------------------
template<typename FE>
__device__ __forceinline__ void select_push(const unsigned (*sb)[4], FE&& fe,
                                            int n0, int m0, int hh, int tid,
                                            unsigned int* h1, unsigned int* h2,
                                            unsigned int* wsum, unsigned int* sh_misc,
                                            uint2* __restrict__ cand,
                                            unsigned int* __restrict__ ctr,
                                            unsigned int cap) {
  const int tx = tid & 15, ty = tid >> 4;

  h1[tid] = 0; h2[tid] = 0;           // safe: prior reads drained >=2 barriers ago
  __syncthreads();
#pragma unroll
  for (int i = 0; i < 8; ++i)
#pragma unroll
    for (int j = 0; j < 4; ++j) atomicAdd(&h1[sb[i][j] >> 24], 1u);
  __syncthreads();
  if (tid < 64) {  // wave 0: coarse threshold scan
    const int b0 = tid * 4;
    const unsigned s4 = h1[b0] + h1[b0 + 1] + h1[b0 + 2] + h1[b0 + 3];
    unsigned suf = s4;
#pragma unroll
    for (int d = 1; d < 64; d <<= 1) {
      const unsigned v = __shfl_down(suf, d, 64);
      if (tid + d < 64) suf += v;
    }
    const unsigned long long mk = __ballot(suf >= 256u);  // suf decreasing -> prefix mask
    const int L = 63 - __builtin_clzll(mk);               // total >= 256 -> mk != 0
    if (tid == L) {
      unsigned cum = suf - s4;        // count strictly above lane L's bins
      unsigned cb = (unsigned)(4 * L), abv = cum;
      for (int b = 4 * L + 3; b >= 4 * L; --b) {
        const unsigned nc = cum + h1[b];
        if (nc >= 256u) { cb = (unsigned)b; abv = cum; break; }
        cum = nc;
      }
      sh_misc[0] = cb; sh_misc[1] = abv;
    }
  }
  __syncthreads();
  const unsigned cb = sh_misc[0], above = sh_misc[1];
#pragma unroll
  for (int i = 0; i < 8; ++i)
#pragma unroll
    for (int j = 0; j < 4; ++j)
      if ((sb[i][j] >> 24) == cb) atomicAdd(&h2[(sb[i][j] >> 16) & 0xFFu], 1u);
  __syncthreads();
  if (tid < 64) {  // wave 0: fine threshold scan
    const int b0 = tid * 4;
    const unsigned s4 = h2[b0] + h2[b0 + 1] + h2[b0 + 2] + h2[b0 + 3];
    unsigned suf = s4;
#pragma unroll
    for (int d = 1; d < 64; d <<= 1) {
      const unsigned v = __shfl_down(suf, d, 64);
      if (tid + d < 64) suf += v;
    }
    const unsigned long long mk = __ballot(above + suf >= 256u);
    const int L = 63 - __builtin_clzll(mk);
    if (tid == L) {
      unsigned cum = above + suf - s4;
      unsigned tb = cb << 8;
      for (int b = 4 * L + 3; b >= 4 * L; --b) {
        cum += h2[b];
        if (cum >= 256u) { tb = (cb << 8) | (unsigned)b; break; }
      }
      const unsigned old = atomicMax(&ctr[2], tb);  // device-scope running bound
      sh_misc[2] = tb > old ? tb : old;
    }
  }
  __syncthreads();
  const unsigned tb16 = sh_misc[2];
  const unsigned F = tb16 > 2u ? tb16 - 2u : 0u;   // 2-fine-bin relaxation

  // candidate push: wave shuffle-scan + 4-entry serial base
  unsigned cnt = 0;
#pragma unroll
  for (int i = 0; i < 8; ++i)
#pragma unroll
    for (int j = 0; j < 4; ++j) cnt += ((sb[i][j] >> 16) >= F) ? 1u : 0u;
  const int lane = tid & 63, wv = tid >> 6;
  unsigned incl = cnt;
#pragma unroll
  for (int d = 1; d < 64; d <<= 1) {
    const unsigned nv = __shfl_up(incl, d, 64);
    if (lane >= d) incl += nv;
  }
  if (lane == 63) wsum[wv] = incl;
  __syncthreads();
  if (tid == 0) {
    unsigned run = 0;
#pragma unroll
    for (int w = 0; w < 4; ++w) { const unsigned c = wsum[w]; wsum[w] = run; run += c; }
    sh_misc[3] = atomicAdd(&ctr[0], run);
  }
  __syncthreads();
  unsigned pos = sh_misc[3] + wsum[wv] + incl - cnt;
#pragma unroll
  for (int i = 0; i < 8; ++i)
#pragma unroll
    for (int j = 0; j < 4; ++j) {
      if ((sb[i][j] >> 16) >= F) {
        if (pos < cap) {
          const unsigned idxv = ((unsigned)(n0 + ty * 8 + i) << 13)
                              | (unsigned)(m0 + hh * 64 + tx * 4 + j);
          cand[pos] = make_uint2(fe(i, j), idxv);   // EXACT key stored
        }
        ++pos;
      }
    }
  __syncthreads();  // h1/h2/wsum/sh_misc reuse in next half
}

// ---------------------------------------------------------------------------
// Pass 2 — R3-proven structure (split dispatches restored).
// RELOAD=true (57/64 block-rows): DB-staged overlap GEMM ov[8][4]; approx f32
//   filter keys; exact f64 keys only for pushed elements. Live ~116 < 128.
// RELOAD=false (7/64): split inner_gemm + exact keys throughout.
// ---------------------------------------------------------------------------
template<bool RELOAD>
__global__ KERNEL_OCC void k_pass2(
    const float* __restrict__ A, const float* __restrict__ B,
    const float* __restrict__ C0, const float* __restrict__ C1,
    const double* __restrict__ invSr, const double* __restrict__ invSc,
    const float* __restrict__ inner, int yoff,
    uint2* __restrict__ cand, unsigned int* __restrict__ ctr, unsigned int cap) {
  __shared__ float SA[2][TK][BT];
  __shared__ float SB[2][TK][BT];
  __shared__ unsigned int h1[256];
  __shared__ unsigned int h2[256];
  __shared__ unsigned int wsum[4];
  __shared__ unsigned int sh_misc[4];
  __shared__ double dsr[BT];
  __shared__ double dsc[BT];
  __shared__ float dsrf[BT];
  __shared__ float dscf[BT];
  const int tid = threadIdx.x;
  const int tx = tid & 15, ty = tid >> 4;
  const int n0 = (blockIdx.y + yoff) * BT, m0 = blockIdx.x * BT;

  // f64 normalizers -> LDS once (same bits) + f32 mirrors for approx keys
  if (tid < BT) {
    const double v = invSr[n0 + tid];
    dsr[tid] = v; dsrf[tid] = (float)v;
  } else {
    const double v = invSc[m0 + tid - BT];
    dsc[tid - BT] = v; dscf[tid - BT] = (float)v;
  }

  const int frow = tid >> 4;        // 0..15 staging row
  const int fn   = (tid & 15) * 8;  // 0..120 staging col

  if (RELOAD) {
#pragma unroll 1
    for (int hh = 0; hh < 2; ++hh) {
      // ---- overlap GEMM for this half, double-buffered staging ----
      float ov[8][4];
#pragma unroll
      for (int i = 0; i < 8; ++i)
#pragma unroll
        for (int j = 0; j < 4; ++j) ov[i][j] = 0.0f;

      const float* c0p = C0 + (size_t)frow * Nn + n0 + fn;
      const float* c1p = C1 + (size_t)frow * Mm + m0 + fn;
      float4 ca0 = *(const float4*)(c0p);
      float4 ca1 = *(const float4*)(c0p + 4);
      float4 cb0 = *(const float4*)(c1p);
      float4 cb1 = *(const float4*)(c1p + 4);
      int p = 0;
      for (int c0i = 0; c0i < Cc; c0i += TK) {
        *(float4*)&SA[p][frow][fn]     = ca0;
        *(float4*)&SA[p][frow][fn + 4] = ca1;
        *(float4*)&SB[p][frow][fn]     = cb0;
        *(float4*)&SB[p][frow][fn + 4] = cb1;
        if (c0i + TK < Cc) {
          const size_t off = (size_t)(c0i + TK);
          ca0 = *(const float4*)(c0p + off * Nn);
          ca1 = *(const float4*)(c0p + off * Nn + 4);
          cb0 = *(const float4*)(c1p + off * Mm);
          cb1 = *(const float4*)(c1p + off * Mm + 4);
        }
        __syncthreads();
#pragma unroll
        for (int g = 0; g < 2; ++g) {
          float th[4][4];
#pragma unroll
          for (int i = 0; i < 4; ++i)
#pragma unroll
            for (int j = 0; j < 4; ++j) th[i][j] = 0.0f;
#pragma unroll
          for (int kk = 0; kk < TK; ++kk) {
            const float4 av = *(const float4*)&SA[p][kk][ty * 8 + g * 4];
            const float4 bv = *(const float4*)&SB[p][kk][hh * 64 + tx * 4];
            const float a[4] = {av.x, av.y, av.z, av.w};
            const float b[4] = {bv.x, bv.y, bv.z, bv.w};
#pragma unroll
            for (int i = 0; i < 4; ++i)
#pragma unroll
              for (int j = 0; j < 4; ++j) th[i][j] = fmaf(a[i], b[j], th[i][j]);
          }
#pragma unroll
          for (int i = 0; i < 4; ++i)
#pragma unroll
            for (int j = 0; j < 4; ++j) ov[g * 4 + i][j] += th[i][j];
        }
        p ^= 1;
      }

      // ---- reload stored f32 inner bits -> APPROX f32 keys ----
      float af[8][4];
      unsigned sb[8][4];
#pragma unroll
      for (int i = 0; i < 8; ++i) {
        *(float4*)&af[i][0] = *(const float4*)(inner + (size_t)(n0 + ty * 8 + i) * Mm
                                               + m0 + hh * 64 + tx * 4);
#pragma unroll
        for (int j = 0; j < 4; ++j) {
          const float ef = __expf(2.0f * af[i][j] - 2.0f);
          const float sf = ef * ef * dsrf[ty * 8 + i] * dscf[hh * 64 + tx * 4 + j]
                         * ov[i][j];
          sb[i][j] = __float_as_uint(sf);
        }
      }
      // exact key on demand (bit-identical chain to R2's epilogue)
      auto fe = [&](int i, int j) -> unsigned {
        const double e = exp(2.0 * (double)af[i][j] - 2.0);
        const double s = e * e * dsr[ty * 8 + i] * dsc[hh * 64 + tx * 4 + j]
                       * (double)ov[i][j];
        return __float_as_uint((float)s);
      };
      select_push(sb, fe, n0, m0, hh, tid, h1, h2, wsum, sh_misc, cand, ctr, cap);
    }
  } else {
    // ---- recompute path: proven per-half structure, exact keys throughout ----
    float acc2[8][8];
    inner_gemm(A, B, n0, m0, tid, SA, SB, acc2);

#pragma unroll 1
    for (int hh = 0; hh < 2; ++hh) {
      float ov[8][4];
#pragma unroll
      for (int i = 0; i < 8; ++i)
#pragma unroll
        for (int j = 0; j < 4; ++j) ov[i][j] = 0.0f;
      for (int c0i = 0; c0i < Cc; c0i += TK) {
        __syncthreads();
        *(float4*)&SA[0][frow][fn]     = *(const float4*)(C0 + (size_t)(c0i + frow) * Nn + n0 + fn);
        *(float4*)&SA[0][frow][fn + 4] = *(const float4*)(C0 + (size_t)(c0i + frow) * Nn + n0 + fn + 4);
        *(float4*)&SB[0][frow][fn]     = *(const float4*)(C1 + (size_t)(c0i + frow) * Mm + m0 + fn);
        *(float4*)&SB[0][frow][fn + 4] = *(const float4*)(C1 + (size_t)(c0i + frow) * Mm + m0 + fn + 4);
        __syncthreads();
#pragma unroll
        for (int g = 0; g < 2; ++g) {
          float th[4][4];
#pragma unroll
          for (int i = 0; i < 4; ++i)
#pragma unroll
            for (int j = 0; j < 4; ++j) th[i][j] = 0.0f;
#pragma unroll
          for (int kk = 0; kk < TK; ++kk) {
            const float4 av = *(const float4*)&SA[0][kk][ty * 8 + g * 4];
            const float4 bv = *(const float4*)&SB[0][kk][hh * 64 + tx * 4];
            const float a[4] = {av.x, av.y, av.z, av.w};
            const float b[4] = {bv.x, bv.y, bv.z, bv.w};
#pragma unroll
            for (int i = 0; i < 4; ++i)
#pragma unroll
              for (int j = 0; j < 4; ++j) th[i][j] = fmaf(a[i], b[j], th[i][j]);
          }
#pragma unroll
          for (int i = 0; i < 4; ++i)
#pragma unroll
            for (int j = 0; j < 4; ++j) ov[g * 4 + i][j] += th[i][j];
        }
      }

      unsigned sb[8][4];
#pragma unroll
      for (int i = 0; i < 8; ++i)
#pragma unroll
        for (int j = 0; j < 4; ++j) {
          const double e = exp(2.0 * (double)acc2[i][hh * 4 + j] - 2.0);
          const double s = e * e * dsr[ty * 8 + i] * dsc[hh * 64 + tx * 4 + j]
                         * (double)ov[i][j];
          sb[i][j] = __float_as_uint(s);
        }
      auto fe = [&](int i, int j) -> unsigned { return sb[i][j]; };
      select_push(sb, fe, n0, m0, hh, tid, h1, h2, wsum, sh_misc, cand, ctr, cap);
    }
  }
}

// ---------------------------------------------------------------------------
// Tail: LDS-aggregated coarse(8b) + fine(8b) histograms -> threshold -> collect
// -> sort. (Unchanged; operates on EXACT cand keys.)
// ---------------------------------------------------------------------------
__global__ __launch_bounds__(256) void k_histc(const uint2* __restrict__ cand,
                                               const unsigned int* __restrict__ ctr,
                                               unsigned int cap,
                                               unsigned int* __restrict__ ghc) {
  __shared__ unsigned int lh[256];
  const int tid = threadIdx.x;
  lh[tid] = 0;
  __syncthreads();
  const unsigned n = min(ctr[0], cap);
  const unsigned stride = gridDim.x * blockDim.x;
  for (unsigned i = blockIdx.x * blockDim.x + tid; i < n; i += stride)
    atomicAdd(&lh[cand[i].x >> 24], 1u);
  __syncthreads();
  if (lh[tid]) atomicAdd(&ghc[tid], lh[tid]);
}

__global__ __launch_bounds__(256) void k_threshc(const unsigned int* __restrict__ ghc,
                                                 unsigned int* __restrict__ ctr) {
  __shared__ unsigned int g[256];
  const int tid = threadIdx.x;
  g[tid] = ghc[tid];
  __syncthreads();
  if (tid == 0) {
    unsigned cum = 0;
    for (int b = 255; b >= 0; --b) {
      cum += g[b];
      if (cum >= 256u) { ctr[4] = (unsigned)b; ctr[5] = cum - g[b]; break; }
    }
  }
}

__global__ __launch_bounds__(256) void k_histf(const uint2* __restrict__ cand,
                                               const unsigned int* __restrict__ ctr,
                                               unsigned int cap,
                                               unsigned int* __restrict__ ghf) {
  __shared__ unsigned int lh[256];
  const int tid = threadIdx.x;
  lh[tid] = 0;
  __syncthreads();
  const unsigned n = min(ctr[0], cap);
  const unsigned cb = ctr[4];
  const unsigned stride = gridDim.x * blockDim.x;
  for (unsigned i = blockIdx.x * blockDim.x + tid; i < n; i += stride) {
    const unsigned k = cand[i].x;
    if ((k >> 24) == cb) atomicAdd(&lh[(k >> 16) & 0xFFu], 1u);
  }
  __syncthreads();
  if (lh[tid]) atomicAdd(&ghf[tid], lh[tid]);
}

__global__ __launch_bounds__(256) void k_threshf(const unsigned int* __restrict__ ghf,
                                                 unsigned int* __restrict__ ctr) {
  __shared__ unsigned int g[256];
  const int tid = threadIdx.x;
  g[tid] = ghf[tid];
  __syncthreads();
  if (tid == 0) {
    const unsigned cb = ctr[4];
    unsigned cum = ctr[5], tb = cb << 8;
    for (int b = 255; b >= 0; --b) {
      cum += g[b];
      if (cum >= 256u) { tb = (cb << 8) | (unsigned)b; break; }
    }
    ctr[3] = tb;
  }
}

__global__ void k_collect(const uint2* __restrict__ cand,
                          unsigned int* __restrict__ ctr,
                          unsigned int cap, uint2* __restrict__ fin) {
  const unsigned n = min(ctr[0], cap);
  const unsigned tb = ctr[3];
  const unsigned stride = gridDim.x * blockDim.x;
  for (unsigned i = blockIdx.x * blockDim.x + threadIdx.x; i < n; i += stride) {
    const uint2 c = cand[i];
    if ((c.x >> 16) >= tb) {
      const unsigned p = atomicAdd(&ctr[1], 1u);
      if (p < FCAP) fin[p] = c;
    }
  }
}

// Sort: pack (key, ~idx) into u64, bitonic desc -> (key desc, idx asc) —
// exactly lax.top_k / np tie semantics on the f32 scores.
__global__ __launch_bounds__(256) void k_sort(const uint2* __restrict__ fin,
                                              const unsigned int* __restrict__ ctr,
                                              float* __restrict__ out) {
  __shared__ unsigned long long kk[FCAP];
  const int tid = threadIdx.x;
  const unsigned n = min(ctr[1], FCAP);
  unsigned np2 = 256;
  while (np2 < n) np2 <<= 1;
  for (unsigned i = tid; i < np2; i += 256) {
    if (i < n) {
      const uint2 c = fin[i];
      kk[i] = ((unsigned long long)c.x << 32) | (unsigned long long)(c.y ^ 0xFFFFFFFFu);
    } else {
      kk[i] = 0ull;
    }
  }
  __syncthreads();
  for (unsigned k2 = 2; k2 <= np2; k2 <<= 1) {
    for (unsigned j = k2 >> 1; j > 0; j >>= 1) {
      for (unsigned i = tid; i < np2; i += 256) {
        const unsigned l = i ^ j;
        if (l > i) {
          const unsigned long long ka = kk[i], kb = kk[l];
          const bool aBefore = ka > kb;
          const bool dsc = (i & k2) == 0;
          const bool sw = dsc ? !aBefore : aBefore;
          if (sw) { kk[i] = kb; kk[l] = ka; }
        }
      }
      __syncthreads();
    }
  }
  {
    const unsigned long long kv = kk[tid];
    const unsigned key = (unsigned)(kv >> 32);
    const unsigned ix  = ((unsigned)kv) ^ 0xFFFFFFFFu;
    out[tid]        = (float)(ix >> 13);      // ref_corr_indices
    out[256 + tid]  = (float)(ix & 8191u);    // src_corr_indices
    out[512 + tid]  = __uint_as_float(key);   // corr_scores (same f32 bits)
  }
}

// ---------------------------------------------------------------------------
extern "C" void kernel_launch(void* const* d_in, const int* in_sizes, int n_in,
                              void* d_out, int out_size, void* d_ws, size_t ws_size,
                              hipStream_t stream) {
  (void)in_sizes; (void)n_in; (void)out_size;
  const float* ref = (const float*)d_in[0];
  const float* src = (const float*)d_in[1];
  const float* c0  = (const float*)d_in[2];
  const float* c1  = (const float*)d_in[3];
  char* ws = (char*)d_ws;
  double* Sr = (double*)(ws + WS_SR);
  double* Sc = (double*)(ws + WS_SC);
  unsigned int* ctr = (unsigned int*)(ws + WS_CTR);
  unsigned int* ghc = (unsigned int*)(ws + WS_GHC);
  unsigned int* ghf = (unsigned int*)(ws + WS_GHF);
  uint2* fin   = (uint2*)(ws + WS_FINAL);
  uint2* cand  = (uint2*)(ws + WS_CAND);
  float* inner = (float*)(ws + WS_INNER);

  const bool store = ws_size >= (size_t)WS_NEED;
  unsigned int cap;
  if (store) {
    cap = (unsigned int)((WS_INNER - WS_CAND) / 8);   // 3,145,728
  } else {
    cap = (ws_size > WS_CAND + 8)
        ? (unsigned int)std::min<size_t>((ws_size - WS_CAND) / 8, (size_t)(16u << 20))
        : 0u;
  }

  hipMemsetAsync(d_ws, 0, (size_t)WS_FINAL, stream);  // Sr, Sc, ctr, ghc, ghf

  dim3 g1(Mm / BT, Nn / BT);
  if (store) {
    k_pass1<true><<<g1, 256, 0, stream>>>(ref, src, Sr, Sc, inner);
    k_recip<<<32, 256, 0, stream>>>(Sr, Sc);
    dim3 gre(Mm / BT, RSTORE / BT);            // 64 x 57 reload blocks
    dim3 grc(Mm / BT, (Nn - RSTORE) / BT);     // 64 x 7 recompute blocks
    k_pass2<true><<<gre, 256, 0, stream>>>(ref, src, c0, c1, Sr, Sc, inner, 0, cand, ctr, cap);
    k_pass2<false><<<grc, 256, 0, stream>>>(ref, src, c0, c1, Sr, Sc, nullptr, RSTORE / BT, cand, ctr, cap);
  } else {
    k_pass1<false><<<g1, 256, 0, stream>>>(ref, src, Sr, Sc, nullptr);
    k_recip<<<32, 256, 0, stream>>>(Sr, Sc);
    k_pass2<false><<<g1, 256, 0, stream>>>(ref, src, c0, c1, Sr, Sc, nullptr, 0, cand, ctr, cap);
  }
  k_histc<<<256, 256, 0, stream>>>(cand, ctr, cap, ghc);
  k_threshc<<<1, 256, 0, stream>>>(ghc, ctr);
  k_histf<<<256, 256, 0, stream>>>(cand, ctr, cap, ghf);
  k_threshf<<<1, 256, 0, stream>>>(ghf, ctr);
  k_collect<<<256, 256, 0, stream>>>(cand, ctr, cap, fin);
  k_sort<<<1, 256, 0, stream>>>(fin, ctr, (float*)d_out);
}